// Round 5
// baseline (376.912 us; speedup 1.0000x reference)
//
#include <hip/hip_runtime.h>
#include <math.h>

#define DIM 8388608
#define NBLK_RED 1024
#define EPS_F 1e-10f
#define WS_SCAL 4096
#define APPLY_GRID 1024
#define APPLY_ITERS (DIM / (APPLY_GRID * 256))   // 32

typedef _Float16 f16x8 __attribute__((ext_vector_type(8)));
typedef _Float16 f16x4 __attribute__((ext_vector_type(4)));
typedef float f32x4 __attribute__((ext_vector_type(4)));

// ws layout (floats):
// [0 .. 4096)    per-block reduction partials: float4 per block {sum g^2, sum d^2, sum g*d, max|g|}
// [4096..4101)   s0, s1, s2, s3 (coeff_k * inv_norm), isq = 1/sqrt(1+it)

__global__ __launch_bounds__(256) void reduce_k(const float4* __restrict__ g4,
                                                const float4* __restrict__ a4,
                                                const float4* __restrict__ b4,
                                                float4* __restrict__ part4) {
    const int N4 = DIM / 4;
    int tid = blockIdx.x * blockDim.x + threadIdx.x;
    int stride = gridDim.x * blockDim.x;
    float ssg = 0.f, ssd = 0.f, sgd = 0.f, mx = 0.f;
    for (int i = tid; i < N4; i += stride) {
        float4 gv = g4[i], av = a4[i], bv = b4[i];
        float d0 = bv.x - av.x, d1 = bv.y - av.y, d2 = bv.z - av.z, d3 = bv.w - av.w;
        ssg = fmaf(gv.x, gv.x, ssg); ssg = fmaf(gv.y, gv.y, ssg);
        ssg = fmaf(gv.z, gv.z, ssg); ssg = fmaf(gv.w, gv.w, ssg);
        ssd = fmaf(d0, d0, ssd); ssd = fmaf(d1, d1, ssd);
        ssd = fmaf(d2, d2, ssd); ssd = fmaf(d3, d3, ssd);
        sgd = fmaf(gv.x, d0, sgd); sgd = fmaf(gv.y, d1, sgd);
        sgd = fmaf(gv.z, d2, sgd); sgd = fmaf(gv.w, d3, sgd);
        mx = fmaxf(mx, fabsf(gv.x)); mx = fmaxf(mx, fabsf(gv.y));
        mx = fmaxf(mx, fabsf(gv.z)); mx = fmaxf(mx, fabsf(gv.w));
    }
    #pragma unroll
    for (int off = 32; off > 0; off >>= 1) {
        ssg += __shfl_down(ssg, off);
        ssd += __shfl_down(ssd, off);
        sgd += __shfl_down(sgd, off);
        mx = fmaxf(mx, __shfl_down(mx, off));
    }
    __shared__ float sm[4][4];
    int lane = threadIdx.x & 63, wid = threadIdx.x >> 6;
    if (lane == 0) { sm[wid][0] = ssg; sm[wid][1] = ssd; sm[wid][2] = sgd; sm[wid][3] = mx; }
    __syncthreads();
    if (threadIdx.x == 0) {
        float t0 = 0.f, t1 = 0.f, t2 = 0.f, t3 = 0.f;
        #pragma unroll
        for (int w = 0; w < 4; ++w) {
            t0 += sm[w][0]; t1 += sm[w][1]; t2 += sm[w][2]; t3 = fmaxf(t3, sm[w][3]);
        }
        part4[blockIdx.x] = make_float4(t0, t1, t2, t3);
    }
}

__global__ __launch_bounds__(64) void mlp_k(float* __restrict__ wsf,
                                            const float* __restrict__ loss_cur,
                                            const float* __restrict__ loss_old,
                                            const int* __restrict__ iter,
                                            const float* __restrict__ lw0, const float* __restrict__ lb0,
                                            const float* __restrict__ lw1, const float* __restrict__ lb1,
                                            const float* __restrict__ lw2, const float* __restrict__ lb2,
                                            const float* __restrict__ lw3, const float* __restrict__ lb3) {
    int t = threadIdx.x;

    // --- final reduction over per-block partials ---
    const float4* part4 = (const float4*)wsf;
    float ssg = 0.f, ssd = 0.f, sgd = 0.f, mx = 0.f;
    for (int b = t; b < NBLK_RED; b += 64) {
        float4 p = part4[b];
        ssg += p.x; ssd += p.y; sgd += p.z; mx = fmaxf(mx, p.w);
    }
    #pragma unroll
    for (int off = 32; off > 0; off >>= 1) {
        ssg += __shfl_down(ssg, off);
        ssd += __shfl_down(ssd, off);
        sgd += __shfl_down(sgd, off);
        mx = fmaxf(mx, __shfl_down(mx, off));
    }
    __shared__ float red[4];
    if (t == 0) { red[0] = ssg; red[1] = ssd; red[2] = sgd; red[3] = mx; }
    __syncthreads();

    __shared__ float buf[32];
    __shared__ float nxt[32];
    float gn = sqrtf(red[0]);
    float dn = sqrtf(red[1]);
    float inv_gn = (gn > EPS_F) ? 1.f / gn : 1.f;
    float inv_dn = (dn > EPS_F) ? 1.f / dn : 1.f;
    float it = (float)iter[0];
    if (t < 6) {
        float f = 0.f;
        if (t == 0) f = log1pf(gn);
        else if (t == 1) f = log1pf(dn);
        else if (t == 2) f = red[2] * inv_gn * inv_dn;
        else if (t == 3) f = red[3] * inv_gn;
        else if (t == 4) f = it;
        else f = logf(loss_cur[0]) - logf(loss_old[0]);
        buf[t] = f;
    }
    __syncthreads();
    float acc;
    if (t < 30) {
        acc = lb0[t];
        #pragma unroll
        for (int c = 0; c < 6; ++c) acc = fmaf(lw0[t * 6 + c], buf[c], acc);
        nxt[t] = fmaxf(acc, 0.f);
    }
    __syncthreads();
    if (t < 20) {
        acc = lb1[t];
        #pragma unroll
        for (int c = 0; c < 30; ++c) acc = fmaf(lw1[t * 30 + c], nxt[c], acc);
        buf[t] = fmaxf(acc, 0.f);
    }
    __syncthreads();
    if (t < 10) {
        acc = lb2[t];
        #pragma unroll
        for (int c = 0; c < 20; ++c) acc = fmaf(lw2[t * 20 + c], buf[c], acc);
        nxt[t] = fmaxf(acc, 0.f);
    }
    __syncthreads();
    if (t < 4) {
        acc = lb3[t];
        #pragma unroll
        for (int c = 0; c < 10; ++c) acc = fmaf(lw3[t * 10 + c], nxt[c], acc);
        float s = ((t & 1) == 0) ? acc * inv_gn : acc * inv_dn;  // t=0,2 g-path; t=1,3 d-path
        wsf[WS_SCAL + t] = s;
    }
    if (t == 0) wsf[WS_SCAL + 4] = rsqrtf(1.f + it);
}

// MFMA conv stack. Per wave: 64 pixels/iter as 4 tiles of 16 columns.
// Weights as A-fragments (16x16x32 f16): A[m=lane&15][k=(lane>>4)*8+j], bias
// folded via constant-1 channel at k=K. B[k=(lane>>4)*8+j][n=lane&15].
// C/D: col=lane&15, row=(lane>>4)*4+reg (m89-verified, dtype-independent).
__global__ __launch_bounds__(256) void apply_k(
    const float* __restrict__ g, const float* __restrict__ a,
    const float* __restrict__ b, const float* __restrict__ gp,
    const float* __restrict__ ex,
    const float* __restrict__ cw0, const float* __restrict__ cb0,
    const float* __restrict__ cw1, const float* __restrict__ cb1,
    const float* __restrict__ cw2, const float* __restrict__ cb2,
    const float* __restrict__ cw3, const float* __restrict__ cb3,
    const float* __restrict__ wsf,
    float* __restrict__ out)
{
    __shared__ _Float16 xbuf[4][4][16][32];  // [wave][tile][n][k]  x at k=0..3, 1.0 at k=4, 0 above
    __shared__ _Float16 hbuf[4][4][16][32];  // H at k=0..19, 1.0 at k=20, 0 above
    __shared__ float    obuf[4][64];

    const int tid  = threadIdx.x;
    const int w    = tid >> 6;
    const int lane = tid & 63;
    const int c    = lane & 15;   // tile column / A row / B col
    const int q    = lane >> 4;   // quad

    // zero-init LDS, then set bias-one channels (persist across iters)
    for (int i = tid; i < 4 * 4 * 16 * 32; i += 256) {
        ((_Float16*)xbuf)[i] = (_Float16)0.f;
        ((_Float16*)hbuf)[i] = (_Float16)0.f;
    }
    __syncthreads();
    {
        int ww = tid >> 6, tt = (tid >> 4) & 3, nn = tid & 15;  // 256 = 4*4*16 exactly
        xbuf[ww][tt][nn][4]  = (_Float16)1.f;
        hbuf[ww][tt][nn][20] = (_Float16)1.f;
    }
    __syncthreads();

    // build weight A-fragments (once; divergent loads, amortized over 32 iters)
    auto mk = [&](const float* W, const float* Bb, int rowbase, int Rtot, int K) -> f16x8 {
        f16x8 r;
        int m = rowbase + c;
        #pragma unroll
        for (int j = 0; j < 8; ++j) {
            int k = q * 8 + j;
            float v = 0.f;
            if (m < Rtot && k <= K) v = (k == K) ? Bb[m] : W[m * K + k];
            r[j] = (_Float16)v;
        }
        return r;
    };
    f16x8 A0a = mk(cw0, cb0, 0, 20, 4);
    f16x8 A0b = mk(cw0, cb0, 16, 20, 4);
    f16x8 A1a = mk(cw1, cb1, 0, 20, 20);
    f16x8 A1b = mk(cw1, cb1, 16, 20, 20);
    f16x8 A2a = mk(cw2, cb2, 0, 20, 20);
    f16x8 A2b = mk(cw2, cb2, 16, 20, 20);
    f16x8 A3  = mk(cw3, cb3, 0, 1, 20);

    float s0 = wsf[WS_SCAL + 0], s1 = wsf[WS_SCAL + 1];
    float s2 = wsf[WS_SCAL + 2], s3 = wsf[WS_SCAL + 3];
    float isq = wsf[WS_SCAL + 4];

    const int stride = APPLY_GRID * 256;
    int p = blockIdx.x * 256 + tid;
    float gv = g[p], av = a[p], bv = b[p], pv = gp[p], evv = ex[p];

    const f32x4 zc = {0.f, 0.f, 0.f, 0.f};

    for (int it = 0; it < APPLY_ITERS; ++it) {
        // stage x for this wave's 64 pixels (lane's pixel -> tile q, col c)
        float de = bv - av;
        f16x4 xv;
        xv[0] = (_Float16)(s0 * pv * gv);
        xv[1] = (_Float16)(s1 * evv * de);
        xv[2] = (_Float16)(s2 * gv);
        xv[3] = (_Float16)(s3 * de);
        *(f16x4*)&xbuf[w][q][c][0] = xv;   // ds_write_b64

        float bv_cur = bv;
        int p_cur = p;
        if (it + 1 < APPLY_ITERS) {        // prefetch next iter (vmcnt stays in flight)
            p += stride;
            gv = g[p]; av = a[p]; bv = b[p]; pv = gp[p]; evv = ex[p];
        }
        asm volatile("s_waitcnt lgkmcnt(0)" ::: "memory");

        #pragma unroll
        for (int t = 0; t < 4; ++t) {
            // layer 0: 4(+1) -> 20
            f16x8 B0 = *(const f16x8*)&xbuf[w][t][c][q * 8];
            f32x4 u0 = __builtin_amdgcn_mfma_f32_16x16x32_f16(A0a, B0, zc, 0, 0, 0);
            f32x4 u1 = __builtin_amdgcn_mfma_f32_16x16x32_f16(A0b, B0, zc, 0, 0, 0);
            f16x4 h0;
            h0[0] = (_Float16)fmaxf(u0[0], 0.f); h0[1] = (_Float16)fmaxf(u0[1], 0.f);
            h0[2] = (_Float16)fmaxf(u0[2], 0.f); h0[3] = (_Float16)fmaxf(u0[3], 0.f);
            *(f16x4*)&hbuf[w][t][c][q * 4] = h0;          // rows 4q..4q+3
            if (lane < 16) {
                f16x4 h1;
                h1[0] = (_Float16)fmaxf(u1[0], 0.f); h1[1] = (_Float16)fmaxf(u1[1], 0.f);
                h1[2] = (_Float16)fmaxf(u1[2], 0.f); h1[3] = (_Float16)fmaxf(u1[3], 0.f);
                *(f16x4*)&hbuf[w][t][c][16] = h1;         // rows 16..19
            }
            asm volatile("s_waitcnt lgkmcnt(0)" ::: "memory");

            // layer 1: 20(+1) -> 20
            f16x8 B1 = *(const f16x8*)&hbuf[w][t][c][q * 8];
            u0 = __builtin_amdgcn_mfma_f32_16x16x32_f16(A1a, B1, zc, 0, 0, 0);
            u1 = __builtin_amdgcn_mfma_f32_16x16x32_f16(A1b, B1, zc, 0, 0, 0);
            h0[0] = (_Float16)fmaxf(u0[0], 0.f); h0[1] = (_Float16)fmaxf(u0[1], 0.f);
            h0[2] = (_Float16)fmaxf(u0[2], 0.f); h0[3] = (_Float16)fmaxf(u0[3], 0.f);
            *(f16x4*)&hbuf[w][t][c][q * 4] = h0;
            if (lane < 16) {
                f16x4 h1;
                h1[0] = (_Float16)fmaxf(u1[0], 0.f); h1[1] = (_Float16)fmaxf(u1[1], 0.f);
                h1[2] = (_Float16)fmaxf(u1[2], 0.f); h1[3] = (_Float16)fmaxf(u1[3], 0.f);
                *(f16x4*)&hbuf[w][t][c][16] = h1;
            }
            asm volatile("s_waitcnt lgkmcnt(0)" ::: "memory");

            // layer 2: 20(+1) -> 20
            f16x8 B2 = *(const f16x8*)&hbuf[w][t][c][q * 8];
            u0 = __builtin_amdgcn_mfma_f32_16x16x32_f16(A2a, B2, zc, 0, 0, 0);
            u1 = __builtin_amdgcn_mfma_f32_16x16x32_f16(A2b, B2, zc, 0, 0, 0);
            h0[0] = (_Float16)fmaxf(u0[0], 0.f); h0[1] = (_Float16)fmaxf(u0[1], 0.f);
            h0[2] = (_Float16)fmaxf(u0[2], 0.f); h0[3] = (_Float16)fmaxf(u0[3], 0.f);
            *(f16x4*)&hbuf[w][t][c][q * 4] = h0;
            if (lane < 16) {
                f16x4 h1;
                h1[0] = (_Float16)fmaxf(u1[0], 0.f); h1[1] = (_Float16)fmaxf(u1[1], 0.f);
                h1[2] = (_Float16)fmaxf(u1[2], 0.f); h1[3] = (_Float16)fmaxf(u1[3], 0.f);
                *(f16x4*)&hbuf[w][t][c][16] = h1;
            }
            asm volatile("s_waitcnt lgkmcnt(0)" ::: "memory");

            // layer 3: 20(+1) -> 1 (row 0 only)
            f16x8 B3 = *(const f16x8*)&hbuf[w][t][c][q * 8];
            u0 = __builtin_amdgcn_mfma_f32_16x16x32_f16(A3, B3, zc, 0, 0, 0);
            if (lane < 16) obuf[w][t * 16 + c] = u0[0];   // row 0, col c
        }
        asm volatile("s_waitcnt lgkmcnt(0)" ::: "memory");
        float dval = obuf[w][lane];
        out[p_cur] = fmaf(dval, isq, bv_cur);
    }
}

extern "C" void kernel_launch(void* const* d_in, const int* in_sizes, int n_in,
                              void* d_out, int out_size, void* d_ws, size_t ws_size,
                              hipStream_t stream) {
    const float* grad    = (const float*)d_in[0];
    const float* state0  = (const float*)d_in[1];
    const float* state1  = (const float*)d_in[2];
    const float* losscur = (const float*)d_in[3];
    const float* lossold = (const float*)d_in[4];
    const int*   iter    = (const int*)d_in[5];
    const float* gparam  = (const float*)d_in[6];
    const float* extrap  = (const float*)d_in[7];
    const float* cw0 = (const float*)d_in[8];  const float* cb0 = (const float*)d_in[9];
    const float* cw1 = (const float*)d_in[10]; const float* cb1 = (const float*)d_in[11];
    const float* cw2 = (const float*)d_in[12]; const float* cb2 = (const float*)d_in[13];
    const float* cw3 = (const float*)d_in[14]; const float* cb3 = (const float*)d_in[15];
    const float* lw0 = (const float*)d_in[16]; const float* lb0 = (const float*)d_in[17];
    const float* lw1 = (const float*)d_in[18]; const float* lb1 = (const float*)d_in[19];
    const float* lw2 = (const float*)d_in[20]; const float* lb2 = (const float*)d_in[21];
    const float* lw3 = (const float*)d_in[22]; const float* lb3 = (const float*)d_in[23];

    float* wsf = (float*)d_ws;
    float* out = (float*)d_out;

    reduce_k<<<NBLK_RED, 256, 0, stream>>>((const float4*)grad, (const float4*)state0,
                                           (const float4*)state1, (float4*)wsf);

    mlp_k<<<1, 64, 0, stream>>>(wsf, losscur, lossold, iter,
                                lw0, lb0, lw1, lb1, lw2, lb2, lw3, lb3);

    apply_k<<<APPLY_GRID, 256, 0, stream>>>(grad, state0, state1, gparam, extrap,
                                            cw0, cb0, cw1, cb1, cw2, cb2, cw3, cb3,
                                            wsf, out);
}

// Round 6
// 332.830 us; speedup vs baseline: 1.1324x; 1.1324x over previous
//
#include <hip/hip_runtime.h>
#include <math.h>

#define DIM 8388608
#define NBLK_RED 1024
#define EPS_F 1e-10f
#define WS_SCAL 4096
#define APPLY_GRID 1024
#define APPLY_ITERS (DIM / (APPLY_GRID * 256))   // 32
#define KP 40   // padded k-dim (f16): 80B row = 20-dword stride -> conflict-free b128 phases

typedef _Float16 f16x8 __attribute__((ext_vector_type(8)));
typedef _Float16 f16x4 __attribute__((ext_vector_type(4)));
typedef float f32x4 __attribute__((ext_vector_type(4)));

// ws layout (floats):
// [0 .. 4096)    per-block reduction partials: float4 per block {sum g^2, sum d^2, sum g*d, max|g|}
// [4096..4101)   s0, s1, s2, s3 (coeff_k * inv_norm), isq = 1/sqrt(1+it)

__global__ __launch_bounds__(256) void reduce_k(const float4* __restrict__ g4,
                                                const float4* __restrict__ a4,
                                                const float4* __restrict__ b4,
                                                float4* __restrict__ part4) {
    const int N4 = DIM / 4;
    int tid = blockIdx.x * blockDim.x + threadIdx.x;
    int stride = gridDim.x * blockDim.x;
    float ssg = 0.f, ssd = 0.f, sgd = 0.f, mx = 0.f;
    for (int i = tid; i < N4; i += stride) {
        float4 gv = g4[i], av = a4[i], bv = b4[i];
        float d0 = bv.x - av.x, d1 = bv.y - av.y, d2 = bv.z - av.z, d3 = bv.w - av.w;
        ssg = fmaf(gv.x, gv.x, ssg); ssg = fmaf(gv.y, gv.y, ssg);
        ssg = fmaf(gv.z, gv.z, ssg); ssg = fmaf(gv.w, gv.w, ssg);
        ssd = fmaf(d0, d0, ssd); ssd = fmaf(d1, d1, ssd);
        ssd = fmaf(d2, d2, ssd); ssd = fmaf(d3, d3, ssd);
        sgd = fmaf(gv.x, d0, sgd); sgd = fmaf(gv.y, d1, sgd);
        sgd = fmaf(gv.z, d2, sgd); sgd = fmaf(gv.w, d3, sgd);
        mx = fmaxf(mx, fabsf(gv.x)); mx = fmaxf(mx, fabsf(gv.y));
        mx = fmaxf(mx, fabsf(gv.z)); mx = fmaxf(mx, fabsf(gv.w));
    }
    #pragma unroll
    for (int off = 32; off > 0; off >>= 1) {
        ssg += __shfl_down(ssg, off);
        ssd += __shfl_down(ssd, off);
        sgd += __shfl_down(sgd, off);
        mx = fmaxf(mx, __shfl_down(mx, off));
    }
    __shared__ float sm[4][4];
    int lane = threadIdx.x & 63, wid = threadIdx.x >> 6;
    if (lane == 0) { sm[wid][0] = ssg; sm[wid][1] = ssd; sm[wid][2] = sgd; sm[wid][3] = mx; }
    __syncthreads();
    if (threadIdx.x == 0) {
        float t0 = 0.f, t1 = 0.f, t2 = 0.f, t3 = 0.f;
        #pragma unroll
        for (int w = 0; w < 4; ++w) {
            t0 += sm[w][0]; t1 += sm[w][1]; t2 += sm[w][2]; t3 = fmaxf(t3, sm[w][3]);
        }
        part4[blockIdx.x] = make_float4(t0, t1, t2, t3);
    }
}

__global__ __launch_bounds__(64) void mlp_k(float* __restrict__ wsf,
                                            const float* __restrict__ loss_cur,
                                            const float* __restrict__ loss_old,
                                            const int* __restrict__ iter,
                                            const float* __restrict__ lw0, const float* __restrict__ lb0,
                                            const float* __restrict__ lw1, const float* __restrict__ lb1,
                                            const float* __restrict__ lw2, const float* __restrict__ lb2,
                                            const float* __restrict__ lw3, const float* __restrict__ lb3) {
    int t = threadIdx.x;

    // --- final reduction over per-block partials ---
    const float4* part4 = (const float4*)wsf;
    float ssg = 0.f, ssd = 0.f, sgd = 0.f, mx = 0.f;
    for (int b = t; b < NBLK_RED; b += 64) {
        float4 p = part4[b];
        ssg += p.x; ssd += p.y; sgd += p.z; mx = fmaxf(mx, p.w);
    }
    #pragma unroll
    for (int off = 32; off > 0; off >>= 1) {
        ssg += __shfl_down(ssg, off);
        ssd += __shfl_down(ssd, off);
        sgd += __shfl_down(sgd, off);
        mx = fmaxf(mx, __shfl_down(mx, off));
    }
    __shared__ float red[4];
    if (t == 0) { red[0] = ssg; red[1] = ssd; red[2] = sgd; red[3] = mx; }
    __syncthreads();

    __shared__ float buf[32];
    __shared__ float nxt[32];
    float gn = sqrtf(red[0]);
    float dn = sqrtf(red[1]);
    float inv_gn = (gn > EPS_F) ? 1.f / gn : 1.f;
    float inv_dn = (dn > EPS_F) ? 1.f / dn : 1.f;
    float it = (float)iter[0];
    if (t < 6) {
        float f = 0.f;
        if (t == 0) f = log1pf(gn);
        else if (t == 1) f = log1pf(dn);
        else if (t == 2) f = red[2] * inv_gn * inv_dn;
        else if (t == 3) f = red[3] * inv_gn;
        else if (t == 4) f = it;
        else f = logf(loss_cur[0]) - logf(loss_old[0]);
        buf[t] = f;
    }
    __syncthreads();
    float acc;
    if (t < 30) {
        acc = lb0[t];
        #pragma unroll
        for (int c = 0; c < 6; ++c) acc = fmaf(lw0[t * 6 + c], buf[c], acc);
        nxt[t] = fmaxf(acc, 0.f);
    }
    __syncthreads();
    if (t < 20) {
        acc = lb1[t];
        #pragma unroll
        for (int c = 0; c < 30; ++c) acc = fmaf(lw1[t * 30 + c], nxt[c], acc);
        buf[t] = fmaxf(acc, 0.f);
    }
    __syncthreads();
    if (t < 10) {
        acc = lb2[t];
        #pragma unroll
        for (int c = 0; c < 20; ++c) acc = fmaf(lw2[t * 20 + c], buf[c], acc);
        nxt[t] = fmaxf(acc, 0.f);
    }
    __syncthreads();
    if (t < 4) {
        acc = lb3[t];
        #pragma unroll
        for (int c = 0; c < 10; ++c) acc = fmaf(lw3[t * 10 + c], nxt[c], acc);
        float s = ((t & 1) == 0) ? acc * inv_gn : acc * inv_dn;  // t=0,2 g-path; t=1,3 d-path
        wsf[WS_SCAL + t] = s;
    }
    if (t == 0) wsf[WS_SCAL + 4] = rsqrtf(1.f + it);
}

// MFMA conv stack. Per wave: 64 pixels/iter as 4 tiles of 16 columns.
// Weights as A-fragments (16x16x32 f16): A[m=lane&15][k=(lane>>4)*8+j], bias
// folded via constant-1 channel at k=K. B[k=(lane>>4)*8+j][n=lane&15].
// C/D: col=lane&15, row=(lane>>4)*4+reg (m89-verified).
// Single LDS buffer per wave/tile, k padded to 40 f16 (20-dword row stride):
// b128 read phases hit start-banks {0,20,8,28,16,4,24,12} = perfect 32-bank
// tiling -> zero conflicts (R5's 64B stride caused 6.7e7 conflict cycles).
// Stale rows between layers are harmless: the A-fragments are zero there.
__global__ __launch_bounds__(256) void apply_k(
    const float* __restrict__ g, const float* __restrict__ a,
    const float* __restrict__ b, const float* __restrict__ gp,
    const float* __restrict__ ex,
    const float* __restrict__ cw0, const float* __restrict__ cb0,
    const float* __restrict__ cw1, const float* __restrict__ cb1,
    const float* __restrict__ cw2, const float* __restrict__ cb2,
    const float* __restrict__ cw3, const float* __restrict__ cb3,
    const float* __restrict__ wsf,
    float* __restrict__ out)
{
    __shared__ _Float16 buf[4][4][16][KP];   // [wave][tile][n][k]
    __shared__ float    obuf[4][64];

    const int tid  = threadIdx.x;
    const int w    = tid >> 6;
    const int lane = tid & 63;
    const int c    = lane & 15;   // tile column / A row / B col
    const int q    = lane >> 4;   // quad

    for (int i = tid; i < 4 * 4 * 16 * KP; i += 256) ((_Float16*)buf)[i] = (_Float16)0.f;
    __syncthreads();

    // build weight A-fragments (once; divergent loads, amortized over 32 iters)
    auto mk = [&](const float* W, const float* Bb, int rowbase, int Rtot, int K) -> f16x8 {
        f16x8 r;
        int m = rowbase + c;
        #pragma unroll
        for (int j = 0; j < 8; ++j) {
            int k = q * 8 + j;
            float v = 0.f;
            if (m < Rtot && k <= K) v = (k == K) ? Bb[m] : W[m * K + k];
            r[j] = (_Float16)v;
        }
        return r;
    };
    f16x8 A0a = mk(cw0, cb0, 0, 20, 4);
    f16x8 A0b = mk(cw0, cb0, 16, 20, 4);
    f16x8 A1a = mk(cw1, cb1, 0, 20, 20);
    f16x8 A1b = mk(cw1, cb1, 16, 20, 20);
    f16x8 A2a = mk(cw2, cb2, 0, 20, 20);
    f16x8 A2b = mk(cw2, cb2, 16, 20, 20);
    f16x8 A3  = mk(cw3, cb3, 0, 1, 20);

    float s0 = wsf[WS_SCAL + 0], s1 = wsf[WS_SCAL + 1];
    float s2 = wsf[WS_SCAL + 2], s3 = wsf[WS_SCAL + 3];
    float isq = wsf[WS_SCAL + 4];

    const int stride = APPLY_GRID * 256;
    int p = blockIdx.x * 256 + tid;
    float gv = g[p], av = a[p], bv = b[p], pv = gp[p], evv = ex[p];

    const f32x4 zc = {0.f, 0.f, 0.f, 0.f};
    const f16x4 biasrow = {(_Float16)1.f, (_Float16)0.f, (_Float16)0.f, (_Float16)0.f};

    auto relu4 = [](f32x4 u) -> f16x4 {
        f16x4 r;
        r[0] = (_Float16)fmaxf(u[0], 0.f); r[1] = (_Float16)fmaxf(u[1], 0.f);
        r[2] = (_Float16)fmaxf(u[2], 0.f); r[3] = (_Float16)fmaxf(u[3], 0.f);
        return r;
    };

    for (int it = 0; it < APPLY_ITERS; ++it) {
        // stage x for this wave's 64 pixels: lane's pixel -> tile q, col c.
        // k=0..3 channels, k=4 bias-one, k=5..7 zero (b128 write).
        float de = bv - av;
        f16x8 xv;
        xv[0] = (_Float16)(s0 * pv * gv);
        xv[1] = (_Float16)(s1 * evv * de);
        xv[2] = (_Float16)(s2 * gv);
        xv[3] = (_Float16)(s3 * de);
        xv[4] = (_Float16)1.f;
        xv[5] = (_Float16)0.f; xv[6] = (_Float16)0.f; xv[7] = (_Float16)0.f;
        *(f16x8*)&buf[w][q][c][0] = xv;

        float bv_cur = bv;
        int p_cur = p;
        if (it + 1 < APPLY_ITERS) {        // prefetch next iter
            p += stride;
            gv = g[p]; av = a[p]; bv = b[p]; pv = gp[p]; evv = ex[p];
        }

        #pragma unroll
        for (int t = 0; t < 4; ++t) {
            // layer 0: 4(+1) -> 20
            f16x8 B0 = *(const f16x8*)&buf[w][t][c][q * 8];
            f32x4 u0 = __builtin_amdgcn_mfma_f32_16x16x32_f16(A0a, B0, zc, 0, 0, 0);
            f32x4 u1 = __builtin_amdgcn_mfma_f32_16x16x32_f16(A0b, B0, zc, 0, 0, 0);
            f16x4 h0 = relu4(u0);
            f16x4 h1 = relu4(u1);            // rows 16+4q+reg; valid data only q=0
            if (q == 1) h1 = biasrow;        // k=20 bias row; q=2,3 write zeros
            *(f16x4*)&buf[w][t][c][q * 4] = h0;
            *(f16x4*)&buf[w][t][c][16 + q * 4] = h1;

            // layer 1: 20(+1) -> 20
            f16x8 B1 = *(const f16x8*)&buf[w][t][c][q * 8];
            u0 = __builtin_amdgcn_mfma_f32_16x16x32_f16(A1a, B1, zc, 0, 0, 0);
            u1 = __builtin_amdgcn_mfma_f32_16x16x32_f16(A1b, B1, zc, 0, 0, 0);
            h0 = relu4(u0);
            h1 = relu4(u1);
            if (q == 1) h1 = biasrow;
            *(f16x4*)&buf[w][t][c][q * 4] = h0;
            *(f16x4*)&buf[w][t][c][16 + q * 4] = h1;

            // layer 2: 20(+1) -> 20
            f16x8 B2 = *(const f16x8*)&buf[w][t][c][q * 8];
            u0 = __builtin_amdgcn_mfma_f32_16x16x32_f16(A2a, B2, zc, 0, 0, 0);
            u1 = __builtin_amdgcn_mfma_f32_16x16x32_f16(A2b, B2, zc, 0, 0, 0);
            h0 = relu4(u0);
            h1 = relu4(u1);
            if (q == 1) h1 = biasrow;
            *(f16x4*)&buf[w][t][c][q * 4] = h0;
            *(f16x4*)&buf[w][t][c][16 + q * 4] = h1;

            // layer 3: 20(+1) -> 1 (row 0 only)
            f16x8 B3 = *(const f16x8*)&buf[w][t][c][q * 8];
            u0 = __builtin_amdgcn_mfma_f32_16x16x32_f16(A3, B3, zc, 0, 0, 0);
            if (lane < 16) obuf[w][t * 16 + c] = u0[0];   // row 0, col c
        }
        float dval = obuf[w][lane];
        out[p_cur] = fmaf(dval, isq, bv_cur);
    }
}

extern "C" void kernel_launch(void* const* d_in, const int* in_sizes, int n_in,
                              void* d_out, int out_size, void* d_ws, size_t ws_size,
                              hipStream_t stream) {
    const float* grad    = (const float*)d_in[0];
    const float* state0  = (const float*)d_in[1];
    const float* state1  = (const float*)d_in[2];
    const float* losscur = (const float*)d_in[3];
    const float* lossold = (const float*)d_in[4];
    const int*   iter    = (const int*)d_in[5];
    const float* gparam  = (const float*)d_in[6];
    const float* extrap  = (const float*)d_in[7];
    const float* cw0 = (const float*)d_in[8];  const float* cb0 = (const float*)d_in[9];
    const float* cw1 = (const float*)d_in[10]; const float* cb1 = (const float*)d_in[11];
    const float* cw2 = (const float*)d_in[12]; const float* cb2 = (const float*)d_in[13];
    const float* cw3 = (const float*)d_in[14]; const float* cb3 = (const float*)d_in[15];
    const float* lw0 = (const float*)d_in[16]; const float* lb0 = (const float*)d_in[17];
    const float* lw1 = (const float*)d_in[18]; const float* lb1 = (const float*)d_in[19];
    const float* lw2 = (const float*)d_in[20]; const float* lb2 = (const float*)d_in[21];
    const float* lw3 = (const float*)d_in[22]; const float* lb3 = (const float*)d_in[23];

    float* wsf = (float*)d_ws;
    float* out = (float*)d_out;

    reduce_k<<<NBLK_RED, 256, 0, stream>>>((const float4*)grad, (const float4*)state0,
                                           (const float4*)state1, (float4*)wsf);

    mlp_k<<<1, 64, 0, stream>>>(wsf, losscur, lossold, iter,
                                lw0, lb0, lw1, lb1, lw2, lb2, lw3, lb3);

    apply_k<<<APPLY_GRID, 256, 0, stream>>>(grad, state0, state1, gparam, extrap,
                                            cw0, cb0, cw1, cb1, cw2, cb2, cw3, cb3,
                                            wsf, out);
}